// Round 1
// baseline (769.289 us; speedup 1.0000x reference)
//
#include <hip/hip_runtime.h>

#define BB 8
#define NN 2048
#define FIN0 16
#define EE 64
#define HH 4
#define DD 16
#define HIDN 128
#define AA 4

// ---------------- scale input features ----------------
__global__ __launch_bounds__(256) void k_scale(const float* __restrict__ nf, float* __restrict__ x0) {
    int i = blockIdx.x * 256 + threadIdx.x;            // B*N*16 total
    int f = i & 15;
    float s = (f == 4 || f == 14 || f == 15) ? 1.0f : ((f == 5) ? (1.0f / 300.0f) : 0.02f);
    x0[i] = nf[i] * s;
}

// ---------------- adjacency -> blocked bitmask (1 = blocked) ----------------
__global__ __launch_bounds__(256) void k_mask(const float* __restrict__ adj, unsigned long long* __restrict__ mb) {
    long long idx = (long long)blockIdx.x * 256 + threadIdx.x;   // b*N*N + r*N + k
    int k = (int)(idx & (NN - 1));
    int r = (int)((idx >> 11) & (NN - 1));
    float a = adj[idx];
    bool blocked = (a == 0.0f) && (k != r);
    unsigned long long m = __ballot(blocked);
    if ((threadIdx.x & 63) == 0) mb[idx >> 6] = m;
}

// ---------------- fold wq@in_w etc. into combined weights ----------------
// CW [fin][192] = {wq,wk,wv}@in_w ; WO [64][64] = mha_ow@op_w ; bO = mha_ob@op_w + op_b
__global__ __launch_bounds__(256) void k_wcomb(
        const float* __restrict__ wq, const float* __restrict__ wk, const float* __restrict__ wv,
        const float* __restrict__ in_w, const float* __restrict__ mow, const float* __restrict__ mob,
        const float* __restrict__ opw, const float* __restrict__ opb,
        float* __restrict__ CW, float* __restrict__ WO, float* __restrict__ bO, int fin) {
    int t = blockIdx.x * 256 + threadIdx.x;
    int total1 = fin * 192;
    if (t < total1) {
        int f = t / 192, j = t % 192;
        const float* w = (j < 64) ? wq : ((j < 128) ? wk : wv);
        float acc = 0.f;
        for (int kk = 0; kk < 64; kk++) acc += w[f * 64 + kk] * in_w[kk * 192 + j];
        CW[t] = acc;
    } else if (t < total1 + 4096) {
        int u = t - total1; int i = u >> 6, j = u & 63;
        float acc = 0.f;
        for (int kk = 0; kk < 64; kk++) acc += mow[i * 64 + kk] * opw[kk * 64 + j];
        WO[u] = acc;
    } else if (t < total1 + 4096 + 64) {
        int j = t - (total1 + 4096);
        float acc = opb[j];
        for (int kk = 0; kk < 64; kk++) acc += mob[kk] * opw[kk * 64 + j];
        bO[j] = acc;
    }
}

// ---------------- fused QKV projection: X[B*N][fin] @ CW[fin][192] + in_b -> Q,K,V [B][H][N][D] ----------------
template <int FINP>
__global__ __launch_bounds__(256) void k_qkv(const float* __restrict__ X, const float* __restrict__ CW,
                                             const float* __restrict__ in_b,
                                             float* __restrict__ Q, float* __restrict__ K, float* __restrict__ V) {
    int lane = threadIdx.x & 63;
    int quarter = threadIdx.x >> 6;                    // 4 col-quarters of 48 cols
    int row = blockIdx.x * 64 + lane;                  // [0, B*N)
    int b = row >> 11, n = row & (NN - 1);
    float xr[FINP];
    const float4* xp = (const float4*)(X + (long long)row * FINP);
#pragma unroll
    for (int i = 0; i < FINP / 4; i++) {
        float4 v = xp[i];
        xr[4 * i] = v.x; xr[4 * i + 1] = v.y; xr[4 * i + 2] = v.z; xr[4 * i + 3] = v.w;
    }
    for (int jq = 0; jq < 12; jq++) {
        int j = quarter * 48 + jq * 4;                 // j%4==0, never crosses a head's d-range
        float4 acc = *(const float4*)(in_b + j);
#pragma unroll
        for (int f = 0; f < FINP; f++) {
            float4 w = *(const float4*)(CW + f * 192 + j);
            acc.x = fmaf(xr[f], w.x, acc.x);
            acc.y = fmaf(xr[f], w.y, acc.y);
            acc.z = fmaf(xr[f], w.z, acc.z);
            acc.w = fmaf(xr[f], w.w, acc.w);
        }
        int which = j >> 6, c = j & 63, h = c >> 4, d = c & 15;
        float* dst = (which == 0) ? Q : ((which == 1) ? K : V);
        *(float4*)(dst + (((long long)(b * HH + h) * NN + n) * DD + d)) = acc;
    }
}

// ---------------- attention: per (b,h), 64 q-rows/block, 4-way split-k ----------------
__global__ __launch_bounds__(256) void k_attn(const float* __restrict__ Q, const float* __restrict__ K,
                                              const float* __restrict__ V,
                                              const unsigned long long* __restrict__ mb,
                                              float* __restrict__ O) {
    __shared__ float sK[4][64 * DD];
    __shared__ float sV[4][64 * DD];
    __shared__ float red[4][64][DD + 1];
    int lane = threadIdx.x & 63;
    int w = threadIdx.x >> 6;                          // k-quarter
    int qb = blockIdx.x, h = blockIdx.y, b = blockIdx.z;
    int q = qb * 64 + lane;
    const float* Qp = Q + ((long long)(b * HH + h) * NN + q) * DD;
    float4 q0 = ((const float4*)Qp)[0], q1 = ((const float4*)Qp)[1],
           q2 = ((const float4*)Qp)[2], q3 = ((const float4*)Qp)[3];
    const float* Kb = K + (long long)(b * HH + h) * NN * DD;
    const float* Vb = V + (long long)(b * HH + h) * NN * DD;
    const unsigned long long* mrow = mb + ((long long)b * NN + q) * (NN / 64);
    float4 o0 = {0, 0, 0, 0}, o1 = {0, 0, 0, 0}, o2 = {0, 0, 0, 0}, o3 = {0, 0, 0, 0};
    float l = 0.f;
    for (int c = 0; c < 8; c++) {
        int kc = w * 512 + c * 64;
        __syncthreads();                               // protect prev iter reads (WAR)
        const float4* srcK = (const float4*)(Kb + (long long)kc * DD);
        const float4* srcV = (const float4*)(Vb + (long long)kc * DD);
        float4* dK = (float4*)sK[w];
        float4* dV = (float4*)sV[w];
#pragma unroll
        for (int i = 0; i < 4; i++) {
            dK[lane + 64 * i] = srcK[lane + 64 * i];
            dV[lane + 64 * i] = srcV[lane + 64 * i];
        }
        __syncthreads();                               // writes visible (RAW)
        unsigned long long mword = mrow[kc >> 6];
#pragma unroll 2
        for (int kk = 0; kk < 64; kk++) {
            const float4* kr = (const float4*)(sK[w] + kk * DD);
            float4 k0 = kr[0], k1 = kr[1], k2 = kr[2], k3 = kr[3];
            float sa = q0.x * k0.x; sa = fmaf(q0.y, k0.y, sa); sa = fmaf(q0.z, k0.z, sa); sa = fmaf(q0.w, k0.w, sa);
            float sb = q1.x * k1.x; sb = fmaf(q1.y, k1.y, sb); sb = fmaf(q1.z, k1.z, sb); sb = fmaf(q1.w, k1.w, sb);
            float sc = q2.x * k2.x; sc = fmaf(q2.y, k2.y, sc); sc = fmaf(q2.z, k2.z, sc); sc = fmaf(q2.w, k2.w, sc);
            float sd = q3.x * k3.x; sd = fmaf(q3.y, k3.y, sd); sd = fmaf(q3.z, k3.z, sd); sd = fmaf(q3.w, k3.w, sd);
            float s = (sa + sb) + (sc + sd);
            float wgt = ((mword >> kk) & 1ULL) ? 0.0f : __expf(s * 0.25f);
            l += wgt;
            const float4* vr = (const float4*)(sV[w] + kk * DD);
            float4 v0 = vr[0], v1 = vr[1], v2 = vr[2], v3 = vr[3];
            o0.x = fmaf(wgt, v0.x, o0.x); o0.y = fmaf(wgt, v0.y, o0.y); o0.z = fmaf(wgt, v0.z, o0.z); o0.w = fmaf(wgt, v0.w, o0.w);
            o1.x = fmaf(wgt, v1.x, o1.x); o1.y = fmaf(wgt, v1.y, o1.y); o1.z = fmaf(wgt, v1.z, o1.z); o1.w = fmaf(wgt, v1.w, o1.w);
            o2.x = fmaf(wgt, v2.x, o2.x); o2.y = fmaf(wgt, v2.y, o2.y); o2.z = fmaf(wgt, v2.z, o2.z); o2.w = fmaf(wgt, v2.w, o2.w);
            o3.x = fmaf(wgt, v3.x, o3.x); o3.y = fmaf(wgt, v3.y, o3.y); o3.z = fmaf(wgt, v3.z, o3.z); o3.w = fmaf(wgt, v3.w, o3.w);
        }
    }
    __syncthreads();
    {
        float* rp = &red[w][lane][0];
        rp[0] = o0.x; rp[1] = o0.y; rp[2] = o0.z; rp[3] = o0.w;
        rp[4] = o1.x; rp[5] = o1.y; rp[6] = o1.z; rp[7] = o1.w;
        rp[8] = o2.x; rp[9] = o2.y; rp[10] = o2.z; rp[11] = o2.w;
        rp[12] = o3.x; rp[13] = o3.y; rp[14] = o3.z; rp[15] = o3.w;
        rp[16] = l;
    }
    __syncthreads();
    if (w == 0) {
        float acc[DD]; float lt = 0.f;
#pragma unroll
        for (int d = 0; d < DD; d++) acc[d] = 0.f;
        for (int s2 = 0; s2 < 4; s2++) {
            const float* pp = &red[s2][lane][0];
#pragma unroll
            for (int d = 0; d < DD; d++) acc[d] += pp[d];
            lt += pp[16];
        }
        float inv = 1.0f / lt;
        float* op = O + (long long)(b * NN + q) * EE + h * DD;
        float4 r0 = {acc[0] * inv, acc[1] * inv, acc[2] * inv, acc[3] * inv};
        float4 r1 = {acc[4] * inv, acc[5] * inv, acc[6] * inv, acc[7] * inv};
        float4 r2 = {acc[8] * inv, acc[9] * inv, acc[10] * inv, acc[11] * inv};
        float4 r3 = {acc[12] * inv, acc[13] * inv, acc[14] * inv, acc[15] * inv};
        ((float4*)op)[0] = r0; ((float4*)op)[1] = r1; ((float4*)op)[2] = r2; ((float4*)op)[3] = r3;
    }
}

// ---------------- out-projection (folded mha_ow@op_w) + ReLU ----------------
__global__ __launch_bounds__(256) void k_out(const float* __restrict__ X, const float* __restrict__ WO,
                                             const float* __restrict__ bO, float* __restrict__ Y) {
    int lane = threadIdx.x & 63, quarter = threadIdx.x >> 6;
    long long row = (long long)blockIdx.x * 64 + lane;
    float xr[64];
    const float4* xp = (const float4*)(X + row * 64);
#pragma unroll
    for (int i = 0; i < 16; i++) {
        float4 t = xp[i];
        xr[4 * i] = t.x; xr[4 * i + 1] = t.y; xr[4 * i + 2] = t.z; xr[4 * i + 3] = t.w;
    }
    for (int jq = 0; jq < 4; jq++) {
        int j = quarter * 16 + jq * 4;
        float4 acc = *(const float4*)(bO + j);
#pragma unroll
        for (int f = 0; f < 64; f++) {
            float4 w4 = *(const float4*)(WO + f * 64 + j);
            acc.x = fmaf(xr[f], w4.x, acc.x);
            acc.y = fmaf(xr[f], w4.y, acc.y);
            acc.z = fmaf(xr[f], w4.z, acc.z);
            acc.w = fmaf(xr[f], w4.w, acc.w);
        }
        acc.x = fmaxf(acc.x, 0.f); acc.y = fmaxf(acc.y, 0.f);
        acc.z = fmaxf(acc.z, 0.f); acc.w = fmaxf(acc.w, 0.f);
        *(float4*)(Y + row * 64 + j) = acc;
    }
}

// ---------------- fused 3-layer MLP head ----------------
__global__ __launch_bounds__(128) void k_head(const float* __restrict__ X,
                                              const float* __restrict__ w1, const float* __restrict__ b1,
                                              const float* __restrict__ w2, const float* __restrict__ b2,
                                              const float* __restrict__ w3, const float* __restrict__ b3,
                                              float* __restrict__ out) {
    __shared__ float Xs[16 * 64];
    __shared__ float H1[16 * 128];
    __shared__ float H2[16 * 128];
    int tid = threadIdx.x;
    long long row0 = (long long)blockIdx.x * 16;
    {
        const float4* src = (const float4*)(X + row0 * 64);
        float4* dst = (float4*)Xs;
        dst[tid] = src[tid];
        dst[tid + 128] = src[tid + 128];
    }
    __syncthreads();
    // h1 = relu(X@w1 + b1), col = tid
    {
        float wr[64];
#pragma unroll
        for (int f = 0; f < 64; f++) wr[f] = w1[f * 128 + tid];
        float bb = b1[tid];
        for (int r = 0; r < 16; r++) {
            const float4* x4 = (const float4*)(Xs + r * 64);
            float a0 = bb, a1 = 0.f, a2 = 0.f, a3 = 0.f;
#pragma unroll
            for (int fq = 0; fq < 16; fq++) {
                float4 xv = x4[fq];
                a0 = fmaf(xv.x, wr[4 * fq], a0);
                a1 = fmaf(xv.y, wr[4 * fq + 1], a1);
                a2 = fmaf(xv.z, wr[4 * fq + 2], a2);
                a3 = fmaf(xv.w, wr[4 * fq + 3], a3);
            }
            H1[r * 128 + tid] = fmaxf((a0 + a1) + (a2 + a3), 0.f);
        }
    }
    __syncthreads();
    // h2 = relu(h1@w2 + b2)
    {
        float wr2[128];
#pragma unroll
        for (int f = 0; f < 128; f++) wr2[f] = w2[f * 128 + tid];
        float bb2 = b2[tid];
        for (int r = 0; r < 16; r++) {
            const float4* h4 = (const float4*)(H1 + r * 128);
            float a0 = bb2, a1 = 0.f, a2 = 0.f, a3 = 0.f;
#pragma unroll
            for (int fq = 0; fq < 32; fq++) {
                float4 xv = h4[fq];
                a0 = fmaf(xv.x, wr2[4 * fq], a0);
                a1 = fmaf(xv.y, wr2[4 * fq + 1], a1);
                a2 = fmaf(xv.z, wr2[4 * fq + 2], a2);
                a3 = fmaf(xv.w, wr2[4 * fq + 3], a3);
            }
            H2[r * 128 + tid] = fmaxf((a0 + a1) + (a2 + a3), 0.f);
        }
    }
    __syncthreads();
    // out = h2@w3 + b3 (A=4)
    if (tid < 64) {
        int r = tid >> 2, a = tid & 3;
        float acc = b3[a];
        for (int f = 0; f < 128; f++) acc = fmaf(H2[r * 128 + f], w3[f * 4 + a], acc);
        out[(row0 + r) * 4 + a] = acc;
    }
}

extern "C" void kernel_launch(void* const* d_in, const int* in_sizes, int n_in,
                              void* d_out, int out_size, void* d_ws, size_t ws_size,
                              hipStream_t stream) {
    const float* nf = (const float*)d_in[0];
    const float* adj = (const float*)d_in[1];
    const float* l0[9]; for (int i = 0; i < 9; i++) l0[i] = (const float*)d_in[2 + i];
    const float* l1[9]; for (int i = 0; i < 9; i++) l1[i] = (const float*)d_in[11 + i];
    const float* hw1 = (const float*)d_in[20]; const float* hb1 = (const float*)d_in[21];
    const float* hw2 = (const float*)d_in[22]; const float* hb2 = (const float*)d_in[23];
    const float* hw3 = (const float*)d_in[24]; const float* hb3 = (const float*)d_in[25];
    float* out = (float*)d_out;

    char* ws = (char*)d_ws;
    size_t off = 0;
    auto alloc = [&](size_t bytes) -> void* {
        void* p = ws + off;
        off = (off + bytes + 255) & ~(size_t)255;
        return p;
    };
    float* x0 = (float*)alloc((size_t)BB * NN * FIN0 * 4);
    unsigned long long* mb = (unsigned long long*)alloc((size_t)BB * NN * NN / 8);
    float* Q = (float*)alloc((size_t)BB * HH * NN * DD * 4);
    float* K = (float*)alloc((size_t)BB * HH * NN * DD * 4);
    float* V = (float*)alloc((size_t)BB * HH * NN * DD * 4);
    float* O = (float*)alloc((size_t)BB * NN * EE * 4);
    float* x1 = (float*)alloc((size_t)BB * NN * EE * 4);
    float* x2 = (float*)alloc((size_t)BB * NN * EE * 4);
    float* CW0 = (float*)alloc(16 * 192 * 4);
    float* CW1 = (float*)alloc(64 * 192 * 4);
    float* WO0 = (float*)alloc(64 * 64 * 4);
    float* WO1 = (float*)alloc(64 * 64 * 4);
    float* bO0 = (float*)alloc(64 * 4);
    float* bO1 = (float*)alloc(64 * 4);

    k_scale<<<BB * NN * FIN0 / 256, 256, 0, stream>>>(nf, x0);
    k_mask<<<(int)((size_t)BB * NN * NN / 256), 256, 0, stream>>>(adj, mb);
    k_wcomb<<<29, 256, 0, stream>>>(l0[0], l0[1], l0[2], l0[3], l0[5], l0[6], l0[7], l0[8], CW0, WO0, bO0, 16);
    k_wcomb<<<65, 256, 0, stream>>>(l1[0], l1[1], l1[2], l1[3], l1[5], l1[6], l1[7], l1[8], CW1, WO1, bO1, 64);

    // layer 0
    k_qkv<16><<<BB * NN / 64, 256, 0, stream>>>(x0, CW0, l0[4], Q, K, V);
    k_attn<<<dim3(NN / 64, HH, BB), 256, 0, stream>>>(Q, K, V, mb, O);
    k_out<<<BB * NN / 64, 256, 0, stream>>>(O, WO0, bO0, x1);
    // layer 1
    k_qkv<64><<<BB * NN / 64, 256, 0, stream>>>(x1, CW1, l1[4], Q, K, V);
    k_attn<<<dim3(NN / 64, HH, BB), 256, 0, stream>>>(Q, K, V, mb, O);
    k_out<<<BB * NN / 64, 256, 0, stream>>>(O, WO1, bO1, x2);
    // head
    k_head<<<BB * NN / 16, 128, 0, stream>>>(x2, hw1, hb1, hw2, hb2, hw3, hb3, out);
}

// Round 2
// 705.064 us; speedup vs baseline: 1.0911x; 1.0911x over previous
//
#include <hip/hip_runtime.h>

#define BB 8
#define NN 2048
#define FIN0 16
#define EE 64
#define HH 4
#define DD 16
#define HIDN 128
#define AA 4

// ---------------- adjacency -> blocked bitmask, TRANSPOSED: mbT[b][kblk][q] ----------------
__global__ __launch_bounds__(256) void k_mask(const float* __restrict__ adj, unsigned long long* __restrict__ mbT) {
    const int ITER = 32;
    for (int it = 0; it < ITER; it++) {
        long long idx = ((long long)blockIdx.x * ITER + it) * 256 + threadIdx.x;  // b*N*N + r*N + k
        int k = (int)(idx & (NN - 1));
        int r = (int)((idx >> 11) & (NN - 1));
        int b = (int)(idx >> 22);
        float a = adj[idx];
        bool blocked = (a == 0.0f) && (k != r);
        unsigned long long m = __ballot(blocked);
        if ((threadIdx.x & 63) == 0) mbT[((long long)b * 32 + (k >> 6)) * NN + r] = m;
    }
}

// ---------------- fold weights: CW = {wq,wk,wv}@in_w (Q cols pre-scaled), WO = mha_ow@op_w ----------------
// Q-column scale = 0.25 * log2(e) so attention can use exp2 directly.
// Layer 0 additionally folds the per-feature input scale into CW rows.
#define QSCALE 0.36067376022224085f   // 0.25 * 1.4426950408889634
__device__ __forceinline__ float sfeat(int f) {
    return (f == 4 || f == 14 || f == 15) ? 1.0f : ((f == 5) ? (1.0f / 300.0f) : 0.02f);
}
__global__ __launch_bounds__(256) void k_wcomb(
        const float* __restrict__ wq0, const float* __restrict__ wk0, const float* __restrict__ wv0,
        const float* __restrict__ inw0, const float* __restrict__ inb0,
        const float* __restrict__ mow0, const float* __restrict__ mob0,
        const float* __restrict__ opw0, const float* __restrict__ opb0,
        const float* __restrict__ wq1, const float* __restrict__ wk1, const float* __restrict__ wv1,
        const float* __restrict__ inw1, const float* __restrict__ inb1,
        const float* __restrict__ mow1, const float* __restrict__ mob1,
        const float* __restrict__ opw1, const float* __restrict__ opb1,
        float* __restrict__ CW0, float* __restrict__ WO0, float* __restrict__ bO0, float* __restrict__ bQ0,
        float* __restrict__ CW1, float* __restrict__ WO1, float* __restrict__ bO1, float* __restrict__ bQ1) {
    int ly = blockIdx.y;
    int fin = ly ? EE : FIN0;
    const float* wq = ly ? wq1 : wq0; const float* wk = ly ? wk1 : wk0; const float* wv = ly ? wv1 : wv0;
    const float* inw = ly ? inw1 : inw0; const float* inb = ly ? inb1 : inb0;
    const float* mow = ly ? mow1 : mow0; const float* mob = ly ? mob1 : mob0;
    const float* opw = ly ? opw1 : opw0; const float* opb = ly ? opb1 : opb0;
    float* CW = ly ? CW1 : CW0; float* WO = ly ? WO1 : WO0;
    float* bO = ly ? bO1 : bO0; float* bQ = ly ? bQ1 : bQ0;

    int t = blockIdx.x * 256 + threadIdx.x;
    int t1 = fin * 192;            // CW region
    int t2 = t1 + 4096;            // WO region
    int t3 = t2 + 64;              // bO region
    int t4 = t3 + 192;             // bQ region
    if (t < t1) {
        int f = t / 192, j = t % 192;
        const float* w = (j < 64) ? wq : ((j < 128) ? wk : wv);
        float acc = 0.f;
        for (int kk = 0; kk < 64; kk++) acc += w[f * 64 + kk] * inw[kk * 192 + j];
        if (j < 64) acc *= QSCALE;
        if (ly == 0) acc *= sfeat(f);
        CW[t] = acc;
    } else if (t < t2) {
        int u = t - t1; int i = u >> 6, j = u & 63;
        float acc = 0.f;
        for (int kk = 0; kk < 64; kk++) acc += mow[i * 64 + kk] * opw[kk * 64 + j];
        WO[u] = acc;
    } else if (t < t3) {
        int j = t - t2;
        float acc = opb[j];
        for (int kk = 0; kk < 64; kk++) acc += mob[kk] * opw[kk * 64 + j];
        bO[j] = acc;
    } else if (t < t4) {
        int j = t - t3;
        bQ[j] = inb[j] * ((j < 64) ? QSCALE : 1.0f);
    }
}

// ---------------- fused QKV projection: X[B*N][fin] @ CW[fin][192] + bQ -> Q,K,V [B][H][N][D] ----------------
template <int FINP>
__global__ __launch_bounds__(256) void k_qkv(const float* __restrict__ X, const float* __restrict__ CW,
                                             const float* __restrict__ bQ,
                                             float* __restrict__ Q, float* __restrict__ K, float* __restrict__ V) {
    int lane = threadIdx.x & 63;
    int quarter = threadIdx.x >> 6;                    // 4 col-quarters of 48 cols
    int row = blockIdx.x * 64 + lane;                  // [0, B*N)
    int b = row >> 11, n = row & (NN - 1);
    float xr[FINP];
    const float4* xp = (const float4*)(X + (long long)row * FINP);
#pragma unroll
    for (int i = 0; i < FINP / 4; i++) {
        float4 v = xp[i];
        xr[4 * i] = v.x; xr[4 * i + 1] = v.y; xr[4 * i + 2] = v.z; xr[4 * i + 3] = v.w;
    }
    for (int jq = 0; jq < 12; jq++) {
        int j = quarter * 48 + jq * 4;                 // j%4==0, never crosses a head's d-range
        float4 acc = *(const float4*)(bQ + j);
#pragma unroll
        for (int f = 0; f < FINP; f++) {
            float4 w = *(const float4*)(CW + f * 192 + j);
            acc.x = fmaf(xr[f], w.x, acc.x);
            acc.y = fmaf(xr[f], w.y, acc.y);
            acc.z = fmaf(xr[f], w.z, acc.z);
            acc.w = fmaf(xr[f], w.w, acc.w);
        }
        int which = j >> 6, c = j & 63, h = c >> 4, d = c & 15;
        float* dst = (which == 0) ? Q : ((which == 1) ? K : V);
        *(float4*)(dst + (((long long)(b * HH + h) * NN + n) * DD + d)) = acc;
    }
}

// ---------------- attention: 128 q-rows/block (2 per lane), 4-way split-k across waves ----------------
__global__ __launch_bounds__(256) void k_attn(const float* __restrict__ Q, const float* __restrict__ K,
                                              const float* __restrict__ V,
                                              const unsigned long long* __restrict__ mbT,
                                              float* __restrict__ O) {
    // union: staging (4 waves x {K,V} x 64x16 = 32768 floats bytes) / reduction (2*4*64*17 floats)
    __shared__ __align__(16) float smem[2 * 4 * 64 * 17];   // 8704 floats = 34816 B
    int lane = threadIdx.x & 63;
    int w = threadIdx.x >> 6;                          // k-quarter
    int qb = blockIdx.x, h = blockIdx.y, b = blockIdx.z;
    int q0 = qb * 128 + lane;                          // q1 = q0 + 64
    const float* Qp0 = Q + ((long long)((b * HH + h) * NN) + q0) * DD;
    const float4* qv0 = (const float4*)Qp0;
    const float4* qv1 = (const float4*)(Qp0 + 64 * DD);
    float4 q00 = qv0[0], q01 = qv0[1], q02 = qv0[2], q03 = qv0[3];
    float4 q10 = qv1[0], q11 = qv1[1], q12 = qv1[2], q13 = qv1[3];
    const float* Kb = K + (long long)(b * HH + h) * NN * DD;
    const float* Vb = V + (long long)(b * HH + h) * NN * DD;
    const unsigned long long* mrow = mbT + (long long)b * 32 * NN;
    float4 o00 = {0,0,0,0}, o01 = {0,0,0,0}, o02 = {0,0,0,0}, o03 = {0,0,0,0};
    float4 o10 = {0,0,0,0}, o11 = {0,0,0,0}, o12 = {0,0,0,0}, o13 = {0,0,0,0};
    float l0 = 0.f, l1 = 0.f;
    float* sK = smem + w * 2048;
    float* sV = sK + 1024;
    for (int c = 0; c < 8; c++) {
        int kc = w * 512 + c * 64;
        __syncthreads();                               // WAR: prev iter reads done
        const float4* srcK = (const float4*)(Kb + (long long)kc * DD);
        const float4* srcV = (const float4*)(Vb + (long long)kc * DD);
#pragma unroll
        for (int i = 0; i < 4; i++) {
            ((float4*)sK)[lane + 64 * i] = srcK[lane + 64 * i];
            ((float4*)sV)[lane + 64 * i] = srcV[lane + 64 * i];
        }
        unsigned long long mw0 = mrow[(long long)(kc >> 6) * NN + q0];        // coalesced across lanes
        unsigned long long mw1 = mrow[(long long)(kc >> 6) * NN + q0 + 64];
        __syncthreads();                               // RAW: staging visible
#pragma unroll 4
        for (int kk = 0; kk < 64; kk++) {
            const float4* kr = (const float4*)(sK + kk * 16);
            float4 k0 = kr[0], k1 = kr[1], k2 = kr[2], k3 = kr[3];
            float cA = q00.x * k0.x;
            cA = fmaf(q00.y, k0.y, cA); cA = fmaf(q00.z, k0.z, cA); cA = fmaf(q00.w, k0.w, cA);
            cA = fmaf(q01.x, k1.x, cA); cA = fmaf(q01.y, k1.y, cA); cA = fmaf(q01.z, k1.z, cA); cA = fmaf(q01.w, k1.w, cA);
            float cB = q02.x * k2.x;
            cB = fmaf(q02.y, k2.y, cB); cB = fmaf(q02.z, k2.z, cB); cB = fmaf(q02.w, k2.w, cB);
            cB = fmaf(q03.x, k3.x, cB); cB = fmaf(q03.y, k3.y, cB); cB = fmaf(q03.w, k3.w, cB); cB = fmaf(q03.z, k3.z, cB);
            float cC = q10.x * k0.x;
            cC = fmaf(q10.y, k0.y, cC); cC = fmaf(q10.z, k0.z, cC); cC = fmaf(q10.w, k0.w, cC);
            cC = fmaf(q11.x, k1.x, cC); cC = fmaf(q11.y, k1.y, cC); cC = fmaf(q11.z, k1.z, cC); cC = fmaf(q11.w, k1.w, cC);
            float cD = q12.x * k2.x;
            cD = fmaf(q12.y, k2.y, cD); cD = fmaf(q12.z, k2.z, cD); cD = fmaf(q12.w, k2.w, cD);
            cD = fmaf(q13.x, k3.x, cD); cD = fmaf(q13.y, k3.y, cD); cD = fmaf(q13.z, k3.z, cD); cD = fmaf(q13.w, k3.w, cD);
            float e0 = __builtin_amdgcn_exp2f(cA + cB);   // scale folded into Q
            float e1 = __builtin_amdgcn_exp2f(cC + cD);
            if ((mw0 >> kk) & 1ULL) e0 = 0.f;
            if ((mw1 >> kk) & 1ULL) e1 = 0.f;
            l0 += e0; l1 += e1;
            const float4* vr = (const float4*)(sV + kk * 16);
            float4 v0 = vr[0], v1 = vr[1], v2 = vr[2], v3 = vr[3];
            o00.x = fmaf(e0, v0.x, o00.x); o00.y = fmaf(e0, v0.y, o00.y); o00.z = fmaf(e0, v0.z, o00.z); o00.w = fmaf(e0, v0.w, o00.w);
            o01.x = fmaf(e0, v1.x, o01.x); o01.y = fmaf(e0, v1.y, o01.y); o01.z = fmaf(e0, v1.z, o01.z); o01.w = fmaf(e0, v1.w, o01.w);
            o02.x = fmaf(e0, v2.x, o02.x); o02.y = fmaf(e0, v2.y, o02.y); o02.z = fmaf(e0, v2.z, o02.z); o02.w = fmaf(e0, v2.w, o02.w);
            o03.x = fmaf(e0, v3.x, o03.x); o03.y = fmaf(e0, v3.y, o03.y); o03.z = fmaf(e0, v3.z, o03.z); o03.w = fmaf(e0, v3.w, o03.w);
            o10.x = fmaf(e1, v0.x, o10.x); o10.y = fmaf(e1, v0.y, o10.y); o10.z = fmaf(e1, v0.z, o10.z); o10.w = fmaf(e1, v0.w, o10.w);
            o11.x = fmaf(e1, v1.x, o11.x); o11.y = fmaf(e1, v1.y, o11.y); o11.z = fmaf(e1, v1.z, o11.z); o11.w = fmaf(e1, v1.w, o11.w);
            o12.x = fmaf(e1, v2.x, o12.x); o12.y = fmaf(e1, v2.y, o12.y); o12.z = fmaf(e1, v2.z, o12.z); o12.w = fmaf(e1, v2.w, o12.w);
            o13.x = fmaf(e1, v3.x, o13.x); o13.y = fmaf(e1, v3.y, o13.y); o13.z = fmaf(e1, v3.z, o13.z); o13.w = fmaf(e1, v3.w, o13.w);
        }
    }
    __syncthreads();                                   // all reads of stage done before overlay
    {
        float* r0 = smem + (((0 * 4 + w) * 64 + lane)) * 17;
        r0[0]=o00.x; r0[1]=o00.y; r0[2]=o00.z; r0[3]=o00.w;
        r0[4]=o01.x; r0[5]=o01.y; r0[6]=o01.z; r0[7]=o01.w;
        r0[8]=o02.x; r0[9]=o02.y; r0[10]=o02.z; r0[11]=o02.w;
        r0[12]=o03.x; r0[13]=o03.y; r0[14]=o03.z; r0[15]=o03.w;
        r0[16]=l0;
        float* r1 = smem + (((1 * 4 + w) * 64 + lane)) * 17;
        r1[0]=o10.x; r1[1]=o10.y; r1[2]=o10.z; r1[3]=o10.w;
        r1[4]=o11.x; r1[5]=o11.y; r1[6]=o11.z; r1[7]=o11.w;
        r1[8]=o12.x; r1[9]=o12.y; r1[10]=o12.z; r1[11]=o12.w;
        r1[12]=o13.x; r1[13]=o13.y; r1[14]=o13.z; r1[15]=o13.w;
        r1[16]=l1;
    }
    __syncthreads();
    if (w < 2) {                                       // wave0 -> q-half0, wave1 -> q-half1
        const float* basep = smem + ((w * 4) * 64 + lane) * 17;
        float acc[DD]; float lt = 0.f;
#pragma unroll
        for (int d = 0; d < DD; d++) acc[d] = 0.f;
#pragma unroll
        for (int s2 = 0; s2 < 4; s2++) {
            const float* pp = basep + s2 * 64 * 17;
#pragma unroll
            for (int d = 0; d < DD; d++) acc[d] += pp[d];
            lt += pp[16];
        }
        float inv = 1.0f / lt;
        int q = qb * 128 + w * 64 + lane;
        float* op = O + (long long)(b * NN + q) * EE + h * DD;
        float4 r0 = {acc[0]*inv, acc[1]*inv, acc[2]*inv, acc[3]*inv};
        float4 r1 = {acc[4]*inv, acc[5]*inv, acc[6]*inv, acc[7]*inv};
        float4 r2 = {acc[8]*inv, acc[9]*inv, acc[10]*inv, acc[11]*inv};
        float4 r3 = {acc[12]*inv, acc[13]*inv, acc[14]*inv, acc[15]*inv};
        ((float4*)op)[0] = r0; ((float4*)op)[1] = r1; ((float4*)op)[2] = r2; ((float4*)op)[3] = r3;
    }
}

// ---------------- out-projection (folded mha_ow@op_w) + ReLU ----------------
__global__ __launch_bounds__(256) void k_out(const float* __restrict__ X, const float* __restrict__ WO,
                                             const float* __restrict__ bO, float* __restrict__ Y) {
    int lane = threadIdx.x & 63, quarter = threadIdx.x >> 6;
    long long row = (long long)blockIdx.x * 64 + lane;
    float xr[64];
    const float4* xp = (const float4*)(X + row * 64);
#pragma unroll
    for (int i = 0; i < 16; i++) {
        float4 t = xp[i];
        xr[4 * i] = t.x; xr[4 * i + 1] = t.y; xr[4 * i + 2] = t.z; xr[4 * i + 3] = t.w;
    }
    for (int jq = 0; jq < 4; jq++) {
        int j = quarter * 16 + jq * 4;
        float4 acc = *(const float4*)(bO + j);
#pragma unroll
        for (int f = 0; f < 64; f++) {
            float4 w4 = *(const float4*)(WO + f * 64 + j);
            acc.x = fmaf(xr[f], w4.x, acc.x);
            acc.y = fmaf(xr[f], w4.y, acc.y);
            acc.z = fmaf(xr[f], w4.z, acc.z);
            acc.w = fmaf(xr[f], w4.w, acc.w);
        }
        acc.x = fmaxf(acc.x, 0.f); acc.y = fmaxf(acc.y, 0.f);
        acc.z = fmaxf(acc.z, 0.f); acc.w = fmaxf(acc.w, 0.f);
        *(float4*)(Y + row * 64 + j) = acc;
    }
}

// ---------------- fused 3-layer MLP head ----------------
__global__ __launch_bounds__(128) void k_head(const float* __restrict__ X,
                                              const float* __restrict__ w1, const float* __restrict__ b1,
                                              const float* __restrict__ w2, const float* __restrict__ b2,
                                              const float* __restrict__ w3, const float* __restrict__ b3,
                                              float* __restrict__ out) {
    __shared__ float Xs[16 * 64];
    __shared__ float H1[16 * 128];
    __shared__ float H2[16 * 128];
    int tid = threadIdx.x;
    long long row0 = (long long)blockIdx.x * 16;
    {
        const float4* src = (const float4*)(X + row0 * 64);
        float4* dst = (float4*)Xs;
        dst[tid] = src[tid];
        dst[tid + 128] = src[tid + 128];
    }
    __syncthreads();
    {
        float wr[64];
#pragma unroll
        for (int f = 0; f < 64; f++) wr[f] = w1[f * 128 + tid];
        float bb = b1[tid];
        for (int r = 0; r < 16; r++) {
            const float4* x4 = (const float4*)(Xs + r * 64);
            float a0 = bb, a1 = 0.f, a2 = 0.f, a3 = 0.f;
#pragma unroll
            for (int fq = 0; fq < 16; fq++) {
                float4 xv = x4[fq];
                a0 = fmaf(xv.x, wr[4 * fq], a0);
                a1 = fmaf(xv.y, wr[4 * fq + 1], a1);
                a2 = fmaf(xv.z, wr[4 * fq + 2], a2);
                a3 = fmaf(xv.w, wr[4 * fq + 3], a3);
            }
            H1[r * 128 + tid] = fmaxf((a0 + a1) + (a2 + a3), 0.f);
        }
    }
    __syncthreads();
    {
        float wr2[128];
#pragma unroll
        for (int f = 0; f < 128; f++) wr2[f] = w2[f * 128 + tid];
        float bb2 = b2[tid];
        for (int r = 0; r < 16; r++) {
            const float4* h4 = (const float4*)(H1 + r * 128);
            float a0 = bb2, a1 = 0.f, a2 = 0.f, a3 = 0.f;
#pragma unroll
            for (int fq = 0; fq < 32; fq++) {
                float4 xv = h4[fq];
                a0 = fmaf(xv.x, wr2[4 * fq], a0);
                a1 = fmaf(xv.y, wr2[4 * fq + 1], a1);
                a2 = fmaf(xv.z, wr2[4 * fq + 2], a2);
                a3 = fmaf(xv.w, wr2[4 * fq + 3], a3);
            }
            H2[r * 128 + tid] = fmaxf((a0 + a1) + (a2 + a3), 0.f);
        }
    }
    __syncthreads();
    if (tid < 64) {
        int r = tid >> 2, a = tid & 3;
        float acc = b3[a];
        for (int f = 0; f < 128; f++) acc = fmaf(H2[r * 128 + f], w3[f * 4 + a], acc);
        out[(row0 + r) * 4 + a] = acc;
    }
}

extern "C" void kernel_launch(void* const* d_in, const int* in_sizes, int n_in,
                              void* d_out, int out_size, void* d_ws, size_t ws_size,
                              hipStream_t stream) {
    const float* nf = (const float*)d_in[0];
    const float* adj = (const float*)d_in[1];
    const float* l0[9]; for (int i = 0; i < 9; i++) l0[i] = (const float*)d_in[2 + i];
    const float* l1[9]; for (int i = 0; i < 9; i++) l1[i] = (const float*)d_in[11 + i];
    const float* hw1 = (const float*)d_in[20]; const float* hb1 = (const float*)d_in[21];
    const float* hw2 = (const float*)d_in[22]; const float* hb2 = (const float*)d_in[23];
    const float* hw3 = (const float*)d_in[24]; const float* hb3 = (const float*)d_in[25];
    float* out = (float*)d_out;

    char* ws = (char*)d_ws;
    size_t off = 0;
    auto alloc = [&](size_t bytes) -> void* {
        void* p = ws + off;
        off = (off + bytes + 255) & ~(size_t)255;
        return p;
    };
    unsigned long long* mbT = (unsigned long long*)alloc((size_t)BB * NN * NN / 8);
    float* Q = (float*)alloc((size_t)BB * HH * NN * DD * 4);
    float* K = (float*)alloc((size_t)BB * HH * NN * DD * 4);
    float* V = (float*)alloc((size_t)BB * HH * NN * DD * 4);
    float* O = (float*)alloc((size_t)BB * NN * EE * 4);
    float* x1 = (float*)alloc((size_t)BB * NN * EE * 4);
    float* x2 = (float*)alloc((size_t)BB * NN * EE * 4);
    float* CW0 = (float*)alloc(16 * 192 * 4);
    float* CW1 = (float*)alloc(64 * 192 * 4);
    float* WO0 = (float*)alloc(64 * 64 * 4);
    float* WO1 = (float*)alloc(64 * 64 * 4);
    float* bO0 = (float*)alloc(64 * 4);
    float* bO1 = (float*)alloc(64 * 4);
    float* bQ0 = (float*)alloc(192 * 4);
    float* bQ1 = (float*)alloc(192 * 4);

    k_mask<<<4096, 256, 0, stream>>>(adj, mbT);
    k_wcomb<<<dim3(65, 2), 256, 0, stream>>>(
        l0[0], l0[1], l0[2], l0[3], l0[4], l0[5], l0[6], l0[7], l0[8],
        l1[0], l1[1], l1[2], l1[3], l1[4], l1[5], l1[6], l1[7], l1[8],
        CW0, WO0, bO0, bQ0, CW1, WO1, bO1, bQ1);

    // layer 0 (feature scale folded into CW0)
    k_qkv<16><<<BB * NN / 64, 256, 0, stream>>>(nf, CW0, bQ0, Q, K, V);
    k_attn<<<dim3(NN / 128, HH, BB), 256, 0, stream>>>(Q, K, V, mbT, O);
    k_out<<<BB * NN / 64, 256, 0, stream>>>(O, WO0, bO0, x1);
    // layer 1
    k_qkv<64><<<BB * NN / 64, 256, 0, stream>>>(x1, CW1, bQ1, Q, K, V);
    k_attn<<<dim3(NN / 128, HH, BB), 256, 0, stream>>>(Q, K, V, mbT, O);
    k_out<<<BB * NN / 64, 256, 0, stream>>>(O, WO1, bO1, x2);
    // head
    k_head<<<BB * NN / 16, 128, 0, stream>>>(x2, hw1, hb1, hw2, hb2, hw3, hb3, out);
}

// Round 3
// 639.210 us; speedup vs baseline: 1.2035x; 1.1030x over previous
//
#include <hip/hip_runtime.h>

#define BB 8
#define NN 2048
#define FIN0 16
#define EE 64
#define HH 4
#define DD 16
#define HIDN 128
#define AA 4

// ---------------- adjacency -> blocked bitmask, TRANSPOSED: mbT[b][kblk][q] ----------------
__global__ __launch_bounds__(256) void k_mask(const float* __restrict__ adj, unsigned long long* __restrict__ mbT) {
    const int ITER = 32;
    for (int it = 0; it < ITER; it++) {
        long long idx = ((long long)blockIdx.x * ITER + it) * 256 + threadIdx.x;  // b*N*N + r*N + k
        int k = (int)(idx & (NN - 1));
        int r = (int)((idx >> 11) & (NN - 1));
        int b = (int)(idx >> 22);
        float a = adj[idx];
        bool blocked = (a == 0.0f) && (k != r);
        unsigned long long m = __ballot(blocked);
        if ((threadIdx.x & 63) == 0) mbT[((long long)b * 32 + (k >> 6)) * NN + r] = m;
    }
}

// ---------------- fold weights: CW = {wq,wk,wv}@in_w (Q cols pre-scaled), WO = mha_ow@op_w ----------------
#define QSCALE 0.36067376022224085f   // 0.25 * log2(e)
__device__ __forceinline__ float sfeat(int f) {
    return (f == 4 || f == 14 || f == 15) ? 1.0f : ((f == 5) ? (1.0f / 300.0f) : 0.02f);
}
__global__ __launch_bounds__(256) void k_wcomb(
        const float* __restrict__ wq0, const float* __restrict__ wk0, const float* __restrict__ wv0,
        const float* __restrict__ inw0, const float* __restrict__ inb0,
        const float* __restrict__ mow0, const float* __restrict__ mob0,
        const float* __restrict__ opw0, const float* __restrict__ opb0,
        const float* __restrict__ wq1, const float* __restrict__ wk1, const float* __restrict__ wv1,
        const float* __restrict__ inw1, const float* __restrict__ inb1,
        const float* __restrict__ mow1, const float* __restrict__ mob1,
        const float* __restrict__ opw1, const float* __restrict__ opb1,
        float* __restrict__ CW0, float* __restrict__ WO0, float* __restrict__ bO0, float* __restrict__ bQ0,
        float* __restrict__ CW1, float* __restrict__ WO1, float* __restrict__ bO1, float* __restrict__ bQ1) {
    int ly = blockIdx.y;
    int fin = ly ? EE : FIN0;
    const float* wq = ly ? wq1 : wq0; const float* wk = ly ? wk1 : wk0; const float* wv = ly ? wv1 : wv0;
    const float* inw = ly ? inw1 : inw0; const float* inb = ly ? inb1 : inb0;
    const float* mow = ly ? mow1 : mow0; const float* mob = ly ? mob1 : mob0;
    const float* opw = ly ? opw1 : opw0; const float* opb = ly ? opb1 : opb0;
    float* CW = ly ? CW1 : CW0; float* WO = ly ? WO1 : WO0;
    float* bO = ly ? bO1 : bO0; float* bQ = ly ? bQ1 : bQ0;

    int t = blockIdx.x * 256 + threadIdx.x;
    int t1 = fin * 192;
    int t2 = t1 + 4096;
    int t3 = t2 + 64;
    int t4 = t3 + 192;
    if (t < t1) {
        int f = t / 192, j = t % 192;
        const float* w = (j < 64) ? wq : ((j < 128) ? wk : wv);
        float acc = 0.f;
        for (int kk = 0; kk < 64; kk++) acc += w[f * 64 + kk] * inw[kk * 192 + j];
        if (j < 64) acc *= QSCALE;
        if (ly == 0) acc *= sfeat(f);
        CW[t] = acc;
    } else if (t < t2) {
        int u = t - t1; int i = u >> 6, j = u & 63;
        float acc = 0.f;
        for (int kk = 0; kk < 64; kk++) acc += mow[i * 64 + kk] * opw[kk * 64 + j];
        WO[u] = acc;
    } else if (t < t3) {
        int j = t - t2;
        float acc = opb[j];
        for (int kk = 0; kk < 64; kk++) acc += mob[kk] * opw[kk * 64 + j];
        bO[j] = acc;
    } else if (t < t4) {
        int j = t - t3;
        bQ[j] = inb[j] * ((j < 64) ? QSCALE : 1.0f);
    }
}

// ---------------- fused QKV projection (layer 0): X[B*N][fin] @ CW + bQ -> Q,K,V [B][H][N][D] ----------------
template <int FINP>
__global__ __launch_bounds__(256) void k_qkv(const float* __restrict__ X, const float* __restrict__ CW,
                                             const float* __restrict__ bQ,
                                             float* __restrict__ Q, float* __restrict__ K, float* __restrict__ V) {
    int lane = threadIdx.x & 63;
    int quarter = threadIdx.x >> 6;
    int row = blockIdx.x * 64 + lane;
    int b = row >> 11, n = row & (NN - 1);
    float xr[FINP];
    const float4* xp = (const float4*)(X + (long long)row * FINP);
#pragma unroll
    for (int i = 0; i < FINP / 4; i++) {
        float4 v = xp[i];
        xr[4 * i] = v.x; xr[4 * i + 1] = v.y; xr[4 * i + 2] = v.z; xr[4 * i + 3] = v.w;
    }
    for (int jq = 0; jq < 12; jq++) {
        int j = quarter * 48 + jq * 4;
        float4 acc = *(const float4*)(bQ + j);
#pragma unroll
        for (int f = 0; f < FINP; f++) {
            float4 w = *(const float4*)(CW + f * 192 + j);
            acc.x = fmaf(xr[f], w.x, acc.x);
            acc.y = fmaf(xr[f], w.y, acc.y);
            acc.z = fmaf(xr[f], w.z, acc.z);
            acc.w = fmaf(xr[f], w.w, acc.w);
        }
        int which = j >> 6, c = j & 63, h = c >> 4, d = c & 15;
        float* dst = (which == 0) ? Q : ((which == 1) ? K : V);
        *(float4*)(dst + (((long long)(b * HH + h) * NN + n) * DD + d)) = acc;
    }
}

// ---------------- attention v3: 256 q-rows/block (4/lane), 8-way k-split, wave-private staging ----------------
// Grid (8, H, B) = 256 blocks x 512 thr. No per-chunk barriers: each wave stages into and
// reads from ONLY its own LDS region; intra-wave write->read ordered by s_waitcnt lgkmcnt(0).
__global__ __launch_bounds__(512, 2) void k_attn(const float* __restrict__ Q, const float* __restrict__ K,
                                                 const float* __restrict__ V,
                                                 const unsigned long long* __restrict__ mbT,
                                                 float* __restrict__ O) {
    // stage: 8 waves x (K 1024 + V 1024 floats) = 16384 floats (first part of smem)
    // partial overlay (after barrier): slot[(w*4+rq)*64+lane]*17, 34816 floats total
    __shared__ float smem[8 * 4 * 64 * 17];
    int lane = threadIdx.x & 63;
    int w = threadIdx.x >> 6;                          // k-eighth owner
    int qb = blockIdx.x, h = blockIdx.y, b = blockIdx.z;
    int qbase = qb * 256;

    const float* Qbh = Q + (long long)(b * HH + h) * NN * DD;
    const float* Kb  = K + (long long)(b * HH + h) * NN * DD;
    const float* Vb  = V + (long long)(b * HH + h) * NN * DD;
    const unsigned long long* mrow = mbT + (long long)b * 32 * NN;

    // q fragments: 4 rows x 16
    float4 qf[4][4];
#pragma unroll
    for (int rq = 0; rq < 4; rq++) {
        const float4* qp = (const float4*)(Qbh + (long long)(qbase + rq * 64 + lane) * DD);
#pragma unroll
        for (int j = 0; j < 4; j++) qf[rq][j] = qp[j];
    }
    float4 oacc[4][4];
#pragma unroll
    for (int rq = 0; rq < 4; rq++)
#pragma unroll
        for (int j = 0; j < 4; j++) oacc[rq][j] = make_float4(0.f, 0.f, 0.f, 0.f);
    float lsum[4] = {0.f, 0.f, 0.f, 0.f};

    float* sK = smem + w * 2048;
    float* sV = sK + 1024;

    for (int c = 0; c < 4; c++) {
        int kc = w * 256 + c * 64;
        // wave-private staging: 64 rows x 16 floats for K and V
        const float4* srcK = (const float4*)(Kb + (long long)kc * DD);
        const float4* srcV = (const float4*)(Vb + (long long)kc * DD);
#pragma unroll
        for (int i = 0; i < 4; i++) {
            ((float4*)sK)[lane + 64 * i] = srcK[lane + 64 * i];
            ((float4*)sV)[lane + 64 * i] = srcV[lane + 64 * i];
        }
        unsigned long long mw[4];
        int kblk = w * 4 + c;
#pragma unroll
        for (int rq = 0; rq < 4; rq++) mw[rq] = mrow[(long long)kblk * NN + qbase + rq * 64 + lane];
        // make this wave's LDS writes visible to all its lanes (no cross-wave sharing)
        asm volatile("s_waitcnt lgkmcnt(0)" ::: "memory");
#pragma unroll 4
        for (int kk = 0; kk < 64; kk++) {
            const float4* kr = (const float4*)(sK + kk * 16);
            float4 k0 = kr[0], k1 = kr[1], k2 = kr[2], k3 = kr[3];
            float e[4];
#pragma unroll
            for (int rq = 0; rq < 4; rq++) {
                float4 a0 = qf[rq][0], a1 = qf[rq][1], a2 = qf[rq][2], a3 = qf[rq][3];
                float sA = a0.x * k0.x;
                sA = fmaf(a0.y, k0.y, sA); sA = fmaf(a0.z, k0.z, sA); sA = fmaf(a0.w, k0.w, sA);
                sA = fmaf(a1.x, k1.x, sA); sA = fmaf(a1.y, k1.y, sA); sA = fmaf(a1.z, k1.z, sA); sA = fmaf(a1.w, k1.w, sA);
                float sB = a2.x * k2.x;
                sB = fmaf(a2.y, k2.y, sB); sB = fmaf(a2.z, k2.z, sB); sB = fmaf(a2.w, k2.w, sB);
                sB = fmaf(a3.x, k3.x, sB); sB = fmaf(a3.y, k3.y, sB); sB = fmaf(a3.z, k3.z, sB); sB = fmaf(a3.w, k3.w, sB);
                float ee = __builtin_amdgcn_exp2f(sA + sB);     // softmax scale folded into Q
                e[rq] = ((mw[rq] >> kk) & 1ULL) ? 0.f : ee;
                lsum[rq] += e[rq];
            }
            const float4* vr = (const float4*)(sV + kk * 16);
            float4 v0 = vr[0], v1 = vr[1], v2 = vr[2], v3 = vr[3];
#pragma unroll
            for (int rq = 0; rq < 4; rq++) {
                float ew = e[rq];
                oacc[rq][0].x = fmaf(ew, v0.x, oacc[rq][0].x); oacc[rq][0].y = fmaf(ew, v0.y, oacc[rq][0].y);
                oacc[rq][0].z = fmaf(ew, v0.z, oacc[rq][0].z); oacc[rq][0].w = fmaf(ew, v0.w, oacc[rq][0].w);
                oacc[rq][1].x = fmaf(ew, v1.x, oacc[rq][1].x); oacc[rq][1].y = fmaf(ew, v1.y, oacc[rq][1].y);
                oacc[rq][1].z = fmaf(ew, v1.z, oacc[rq][1].z); oacc[rq][1].w = fmaf(ew, v1.w, oacc[rq][1].w);
                oacc[rq][2].x = fmaf(ew, v2.x, oacc[rq][2].x); oacc[rq][2].y = fmaf(ew, v2.y, oacc[rq][2].y);
                oacc[rq][2].z = fmaf(ew, v2.z, oacc[rq][2].z); oacc[rq][2].w = fmaf(ew, v2.w, oacc[rq][2].w);
                oacc[rq][3].x = fmaf(ew, v3.x, oacc[rq][3].x); oacc[rq][3].y = fmaf(ew, v3.y, oacc[rq][3].y);
                oacc[rq][3].z = fmaf(ew, v3.z, oacc[rq][3].z); oacc[rq][3].w = fmaf(ew, v3.w, oacc[rq][3].w);
            }
        }
    }
    __syncthreads();                                   // all staging reads done before overlay
#pragma unroll
    for (int rq = 0; rq < 4; rq++) {
        float* rp = smem + (((w * 4 + rq) * 64 + lane)) * 17;   // stride 17: 2 lanes/bank, conflict-free
#pragma unroll
        for (int j = 0; j < 4; j++) {
            rp[4 * j + 0] = oacc[rq][j].x; rp[4 * j + 1] = oacc[rq][j].y;
            rp[4 * j + 2] = oacc[rq][j].z; rp[4 * j + 3] = oacc[rq][j].w;
        }
        rp[16] = lsum[rq];
    }
    __syncthreads();
    if (w < 4) {                                       // wave w combines q-group rq=w
        int rq = w;
        float acc[DD]; float lt = 0.f;
#pragma unroll
        for (int d = 0; d < DD; d++) acc[d] = 0.f;
#pragma unroll
        for (int p = 0; p < 8; p++) {
            const float* pp = smem + (((p * 4 + rq) * 64 + lane)) * 17;
#pragma unroll
            for (int d = 0; d < DD; d++) acc[d] += pp[d];
            lt += pp[16];
        }
        float inv = 1.0f / lt;
        int q = qbase + rq * 64 + lane;
        float* op = O + (long long)(b * NN + q) * EE + h * DD;
        float4 r0 = {acc[0]*inv, acc[1]*inv, acc[2]*inv, acc[3]*inv};
        float4 r1 = {acc[4]*inv, acc[5]*inv, acc[6]*inv, acc[7]*inv};
        float4 r2 = {acc[8]*inv, acc[9]*inv, acc[10]*inv, acc[11]*inv};
        float4 r3 = {acc[12]*inv, acc[13]*inv, acc[14]*inv, acc[15]*inv};
        ((float4*)op)[0] = r0; ((float4*)op)[1] = r1; ((float4*)op)[2] = r2; ((float4*)op)[3] = r3;
    }
}

// ---------------- out-projection + ReLU (standalone, used for layer 1) ----------------
__global__ __launch_bounds__(256) void k_out(const float* __restrict__ X, const float* __restrict__ WO,
                                             const float* __restrict__ bO, float* __restrict__ Y) {
    int lane = threadIdx.x & 63, quarter = threadIdx.x >> 6;
    long long row = (long long)blockIdx.x * 64 + lane;
    float xr[64];
    const float4* xp = (const float4*)(X + row * 64);
#pragma unroll
    for (int i = 0; i < 16; i++) {
        float4 t = xp[i];
        xr[4 * i] = t.x; xr[4 * i + 1] = t.y; xr[4 * i + 2] = t.z; xr[4 * i + 3] = t.w;
    }
    for (int jq = 0; jq < 4; jq++) {
        int j = quarter * 16 + jq * 4;
        float4 acc = *(const float4*)(bO + j);
#pragma unroll
        for (int f = 0; f < 64; f++) {
            float4 w4 = *(const float4*)(WO + f * 64 + j);
            acc.x = fmaf(xr[f], w4.x, acc.x);
            acc.y = fmaf(xr[f], w4.y, acc.y);
            acc.z = fmaf(xr[f], w4.z, acc.z);
            acc.w = fmaf(xr[f], w4.w, acc.w);
        }
        acc.x = fmaxf(acc.x, 0.f); acc.y = fmaxf(acc.y, 0.f);
        acc.z = fmaxf(acc.z, 0.f); acc.w = fmaxf(acc.w, 0.f);
        *(float4*)(Y + row * 64 + j) = acc;
    }
}

// ---------------- fused: out-proj(L0)+ReLU -> QKV proj (L1), x1 never touches HBM ----------------
__global__ __launch_bounds__(256) void k_outqkv(const float* __restrict__ O, const float* __restrict__ WO,
                                                const float* __restrict__ bO,
                                                const float* __restrict__ CW, const float* __restrict__ bQ,
                                                float* __restrict__ Q, float* __restrict__ K, float* __restrict__ V) {
    __shared__ float xs[64 * 68];                      // stride 68: b128-aligned, conflict-free
    int lane = threadIdx.x & 63, quarter = threadIdx.x >> 6;
    long long row = (long long)blockIdx.x * 64 + lane;
    int b = (int)(row >> 11), n = (int)(row & (NN - 1));
    {
        float xr[64];
        const float4* xp = (const float4*)(O + row * 64);
#pragma unroll
        for (int i = 0; i < 16; i++) {
            float4 t = xp[i];
            xr[4 * i] = t.x; xr[4 * i + 1] = t.y; xr[4 * i + 2] = t.z; xr[4 * i + 3] = t.w;
        }
        for (int jq = 0; jq < 4; jq++) {
            int j = quarter * 16 + jq * 4;
            float4 acc = *(const float4*)(bO + j);
#pragma unroll
            for (int f = 0; f < 64; f++) {
                float4 w4 = *(const float4*)(WO + f * 64 + j);
                acc.x = fmaf(xr[f], w4.x, acc.x);
                acc.y = fmaf(xr[f], w4.y, acc.y);
                acc.z = fmaf(xr[f], w4.z, acc.z);
                acc.w = fmaf(xr[f], w4.w, acc.w);
            }
            acc.x = fmaxf(acc.x, 0.f); acc.y = fmaxf(acc.y, 0.f);
            acc.z = fmaxf(acc.z, 0.f); acc.w = fmaxf(acc.w, 0.f);
            *(float4*)(xs + lane * 68 + j) = acc;
        }
    }
    __syncthreads();
    {
        float xr[64];
        const float4* xp = (const float4*)(xs + lane * 68);
#pragma unroll
        for (int i = 0; i < 16; i++) {
            float4 t = xp[i];
            xr[4 * i] = t.x; xr[4 * i + 1] = t.y; xr[4 * i + 2] = t.z; xr[4 * i + 3] = t.w;
        }
        for (int jq = 0; jq < 12; jq++) {
            int j = quarter * 48 + jq * 4;
            float4 acc = *(const float4*)(bQ + j);
#pragma unroll
            for (int f = 0; f < 64; f++) {
                float4 w4 = *(const float4*)(CW + f * 192 + j);
                acc.x = fmaf(xr[f], w4.x, acc.x);
                acc.y = fmaf(xr[f], w4.y, acc.y);
                acc.z = fmaf(xr[f], w4.z, acc.z);
                acc.w = fmaf(xr[f], w4.w, acc.w);
            }
            int which = j >> 6, c = j & 63, h = c >> 4, d = c & 15;
            float* dst = (which == 0) ? Q : ((which == 1) ? K : V);
            *(float4*)(dst + (((long long)(b * HH + h) * NN + n) * DD + d)) = acc;
        }
    }
}

// ---------------- fused 3-layer MLP head ----------------
__global__ __launch_bounds__(128) void k_head(const float* __restrict__ X,
                                              const float* __restrict__ w1, const float* __restrict__ b1,
                                              const float* __restrict__ w2, const float* __restrict__ b2,
                                              const float* __restrict__ w3, const float* __restrict__ b3,
                                              float* __restrict__ out) {
    __shared__ float Xs[16 * 64];
    __shared__ float H1[16 * 128];
    __shared__ float H2[16 * 128];
    int tid = threadIdx.x;
    long long row0 = (long long)blockIdx.x * 16;
    {
        const float4* src = (const float4*)(X + row0 * 64);
        float4* dst = (float4*)Xs;
        dst[tid] = src[tid];
        dst[tid + 128] = src[tid + 128];
    }
    __syncthreads();
    {
        float wr[64];
#pragma unroll
        for (int f = 0; f < 64; f++) wr[f] = w1[f * 128 + tid];
        float bb = b1[tid];
        for (int r = 0; r < 16; r++) {
            const float4* x4 = (const float4*)(Xs + r * 64);
            float a0 = bb, a1 = 0.f, a2 = 0.f, a3 = 0.f;
#pragma unroll
            for (int fq = 0; fq < 16; fq++) {
                float4 xv = x4[fq];
                a0 = fmaf(xv.x, wr[4 * fq], a0);
                a1 = fmaf(xv.y, wr[4 * fq + 1], a1);
                a2 = fmaf(xv.z, wr[4 * fq + 2], a2);
                a3 = fmaf(xv.w, wr[4 * fq + 3], a3);
            }
            H1[r * 128 + tid] = fmaxf((a0 + a1) + (a2 + a3), 0.f);
        }
    }
    __syncthreads();
    {
        float wr2[128];
#pragma unroll
        for (int f = 0; f < 128; f++) wr2[f] = w2[f * 128 + tid];
        float bb2 = b2[tid];
        for (int r = 0; r < 16; r++) {
            const float4* h4 = (const float4*)(H1 + r * 128);
            float a0 = bb2, a1 = 0.f, a2 = 0.f, a3 = 0.f;
#pragma unroll
            for (int fq = 0; fq < 32; fq++) {
                float4 xv = h4[fq];
                a0 = fmaf(xv.x, wr2[4 * fq], a0);
                a1 = fmaf(xv.y, wr2[4 * fq + 1], a1);
                a2 = fmaf(xv.z, wr2[4 * fq + 2], a2);
                a3 = fmaf(xv.w, wr2[4 * fq + 3], a3);
            }
            H2[r * 128 + tid] = fmaxf((a0 + a1) + (a2 + a3), 0.f);
        }
    }
    __syncthreads();
    if (tid < 64) {
        int r = tid >> 2, a = tid & 3;
        float acc = b3[a];
        for (int f = 0; f < 128; f++) acc = fmaf(H2[r * 128 + f], w3[f * 4 + a], acc);
        out[(row0 + r) * 4 + a] = acc;
    }
}

extern "C" void kernel_launch(void* const* d_in, const int* in_sizes, int n_in,
                              void* d_out, int out_size, void* d_ws, size_t ws_size,
                              hipStream_t stream) {
    const float* nf = (const float*)d_in[0];
    const float* adj = (const float*)d_in[1];
    const float* l0[9]; for (int i = 0; i < 9; i++) l0[i] = (const float*)d_in[2 + i];
    const float* l1[9]; for (int i = 0; i < 9; i++) l1[i] = (const float*)d_in[11 + i];
    const float* hw1 = (const float*)d_in[20]; const float* hb1 = (const float*)d_in[21];
    const float* hw2 = (const float*)d_in[22]; const float* hb2 = (const float*)d_in[23];
    const float* hw3 = (const float*)d_in[24]; const float* hb3 = (const float*)d_in[25];
    float* out = (float*)d_out;

    char* ws = (char*)d_ws;
    size_t off = 0;
    auto alloc = [&](size_t bytes) -> void* {
        void* p = ws + off;
        off = (off + bytes + 255) & ~(size_t)255;
        return p;
    };
    unsigned long long* mbT = (unsigned long long*)alloc((size_t)BB * NN * NN / 8);
    float* Q = (float*)alloc((size_t)BB * HH * NN * DD * 4);
    float* K = (float*)alloc((size_t)BB * HH * NN * DD * 4);
    float* V = (float*)alloc((size_t)BB * HH * NN * DD * 4);
    float* O = (float*)alloc((size_t)BB * NN * EE * 4);
    float* x2 = (float*)alloc((size_t)BB * NN * EE * 4);
    float* CW0 = (float*)alloc(16 * 192 * 4);
    float* CW1 = (float*)alloc(64 * 192 * 4);
    float* WO0 = (float*)alloc(64 * 64 * 4);
    float* WO1 = (float*)alloc(64 * 64 * 4);
    float* bO0 = (float*)alloc(64 * 4);
    float* bO1 = (float*)alloc(64 * 4);
    float* bQ0 = (float*)alloc(192 * 4);
    float* bQ1 = (float*)alloc(192 * 4);

    k_mask<<<4096, 256, 0, stream>>>(adj, mbT);
    k_wcomb<<<dim3(65, 2), 256, 0, stream>>>(
        l0[0], l0[1], l0[2], l0[3], l0[4], l0[5], l0[6], l0[7], l0[8],
        l1[0], l1[1], l1[2], l1[3], l1[4], l1[5], l1[6], l1[7], l1[8],
        CW0, WO0, bO0, bQ0, CW1, WO1, bO1, bQ1);

    // layer 0 (feature scale folded into CW0)
    k_qkv<16><<<BB * NN / 64, 256, 0, stream>>>(nf, CW0, bQ0, Q, K, V);
    k_attn<<<dim3(NN / 256, HH, BB), 512, 0, stream>>>(Q, K, V, mbT, O);
    // fused: out-proj L0 + QKV proj L1
    k_outqkv<<<BB * NN / 64, 256, 0, stream>>>(O, WO0, bO0, CW1, bQ1, Q, K, V);
    k_attn<<<dim3(NN / 256, HH, BB), 512, 0, stream>>>(Q, K, V, mbT, O);
    k_out<<<BB * NN / 64, 256, 0, stream>>>(O, WO1, bO1, x2);
    // head
    k_head<<<BB * NN / 16, 128, 0, stream>>>(x2, hw1, hb1, hw2, hb2, hw3, hb3, out);
}

// Round 4
// 609.995 us; speedup vs baseline: 1.2611x; 1.0479x over previous
//
#include <hip/hip_runtime.h>

#define BB 8
#define NN 2048
#define FIN0 16
#define EE 64
#define HH 4
#define DD 16
#define HIDN 128
#define AA 4

// ---------------- adjacency -> blocked bitmask, TRANSPOSED: mbT[b][kblk][q] ----------------
__global__ __launch_bounds__(256) void k_mask(const float* __restrict__ adj, unsigned long long* __restrict__ mbT) {
    const int ITER = 32;
    for (int it = 0; it < ITER; it++) {
        long long idx = ((long long)blockIdx.x * ITER + it) * 256 + threadIdx.x;  // b*N*N + r*N + k
        int k = (int)(idx & (NN - 1));
        int r = (int)((idx >> 11) & (NN - 1));
        int b = (int)(idx >> 22);
        float a = adj[idx];
        bool blocked = (a == 0.0f) && (k != r);
        unsigned long long m = __ballot(blocked);
        if ((threadIdx.x & 63) == 0) mbT[((long long)b * 32 + (k >> 6)) * NN + r] = m;
    }
}

// ---------------- fold weights: CW = {wq,wk,wv}@in_w (Q cols pre-scaled), WO = mha_ow@op_w ----------------
#define QSCALE 0.36067376022224085f   // 0.25 * log2(e)
__device__ __forceinline__ float sfeat(int f) {
    return (f == 4 || f == 14 || f == 15) ? 1.0f : ((f == 5) ? (1.0f / 300.0f) : 0.02f);
}
__global__ __launch_bounds__(256) void k_wcomb(
        const float* __restrict__ wq0, const float* __restrict__ wk0, const float* __restrict__ wv0,
        const float* __restrict__ inw0, const float* __restrict__ inb0,
        const float* __restrict__ mow0, const float* __restrict__ mob0,
        const float* __restrict__ opw0, const float* __restrict__ opb0,
        const float* __restrict__ wq1, const float* __restrict__ wk1, const float* __restrict__ wv1,
        const float* __restrict__ inw1, const float* __restrict__ inb1,
        const float* __restrict__ mow1, const float* __restrict__ mob1,
        const float* __restrict__ opw1, const float* __restrict__ opb1,
        float* __restrict__ CW0, float* __restrict__ WO0, float* __restrict__ bO0, float* __restrict__ bQ0,
        float* __restrict__ CW1, float* __restrict__ WO1, float* __restrict__ bO1, float* __restrict__ bQ1) {
    int ly = blockIdx.y;
    int fin = ly ? EE : FIN0;
    const float* wq = ly ? wq1 : wq0; const float* wk = ly ? wk1 : wk0; const float* wv = ly ? wv1 : wv0;
    const float* inw = ly ? inw1 : inw0; const float* inb = ly ? inb1 : inb0;
    const float* mow = ly ? mow1 : mow0; const float* mob = ly ? mob1 : mob0;
    const float* opw = ly ? opw1 : opw0; const float* opb = ly ? opb1 : opb0;
    float* CW = ly ? CW1 : CW0; float* WO = ly ? WO1 : WO0;
    float* bO = ly ? bO1 : bO0; float* bQ = ly ? bQ1 : bQ0;

    int t = blockIdx.x * 256 + threadIdx.x;
    int t1 = fin * 192;
    int t2 = t1 + 4096;
    int t3 = t2 + 64;
    int t4 = t3 + 192;
    if (t < t1) {
        int f = t / 192, j = t % 192;
        const float* w = (j < 64) ? wq : ((j < 128) ? wk : wv);
        float acc = 0.f;
        for (int kk = 0; kk < 64; kk++) acc += w[f * 64 + kk] * inw[kk * 192 + j];
        if (j < 64) acc *= QSCALE;
        if (ly == 0) acc *= sfeat(f);
        CW[t] = acc;
    } else if (t < t2) {
        int u = t - t1; int i = u >> 6, j = u & 63;
        float acc = 0.f;
        for (int kk = 0; kk < 64; kk++) acc += mow[i * 64 + kk] * opw[kk * 64 + j];
        WO[u] = acc;
    } else if (t < t3) {
        int j = t - t2;
        float acc = opb[j];
        for (int kk = 0; kk < 64; kk++) acc += mob[kk] * opw[kk * 64 + j];
        bO[j] = acc;
    } else if (t < t4) {
        int j = t - t3;
        bQ[j] = inb[j] * ((j < 64) ? QSCALE : 1.0f);
    }
}

// ---------------- fused QKV projection (layer 0): X[B*N][fin] @ CW + bQ -> Q,K,V [B][H][N][D] ----------------
template <int FINP>
__global__ __launch_bounds__(256) void k_qkv(const float* __restrict__ X, const float* __restrict__ CW,
                                             const float* __restrict__ bQ,
                                             float* __restrict__ Q, float* __restrict__ K, float* __restrict__ V) {
    int lane = threadIdx.x & 63;
    int quarter = threadIdx.x >> 6;
    int row = blockIdx.x * 64 + lane;
    int b = row >> 11, n = row & (NN - 1);
    float xr[FINP];
    const float4* xp = (const float4*)(X + (long long)row * FINP);
#pragma unroll
    for (int i = 0; i < FINP / 4; i++) {
        float4 v = xp[i];
        xr[4 * i] = v.x; xr[4 * i + 1] = v.y; xr[4 * i + 2] = v.z; xr[4 * i + 3] = v.w;
    }
    for (int jq = 0; jq < 12; jq++) {
        int j = quarter * 48 + jq * 4;
        float4 acc = *(const float4*)(bQ + j);
#pragma unroll
        for (int f = 0; f < FINP; f++) {
            float4 w = *(const float4*)(CW + f * 192 + j);
            acc.x = fmaf(xr[f], w.x, acc.x);
            acc.y = fmaf(xr[f], w.y, acc.y);
            acc.z = fmaf(xr[f], w.z, acc.z);
            acc.w = fmaf(xr[f], w.w, acc.w);
        }
        int which = j >> 6, c = j & 63, h = c >> 4, d = c & 15;
        float* dst = (which == 0) ? Q : ((which == 1) ? K : V);
        *(float4*)(dst + (((long long)(b * HH + h) * NN + n) * DD + d)) = acc;
    }
}

// ---------------- attention v4: v3 + register prefetch of next chunk (K/V/mask) ----------------
// Grid (8, H, B) = 256 blocks x 512 thr. Wave-private staging, no per-chunk barriers.
// Next chunk's K/V rows + mask words are loaded into registers DURING current chunk's
// compute, so chunk-boundary global latency is off the critical path.
__global__ __launch_bounds__(512, 2) void k_attn(const float* __restrict__ Q, const float* __restrict__ K,
                                                 const float* __restrict__ V,
                                                 const unsigned long long* __restrict__ mbT,
                                                 float* __restrict__ O) {
    __shared__ float smem[8 * 4 * 64 * 17];            // stage region overlaid by reduction region
    int lane = threadIdx.x & 63;
    int w = threadIdx.x >> 6;                          // k-eighth owner
    int qb = blockIdx.x, h = blockIdx.y, b = blockIdx.z;
    int qbase = qb * 256;

    const float* Qbh = Q + (long long)(b * HH + h) * NN * DD;
    const float* Kb  = K + (long long)(b * HH + h) * NN * DD;
    const float* Vb  = V + (long long)(b * HH + h) * NN * DD;
    const unsigned long long* mrow = mbT + (long long)b * 32 * NN;

    float4 qf[4][4];
#pragma unroll
    for (int rq = 0; rq < 4; rq++) {
        const float4* qp = (const float4*)(Qbh + (long long)(qbase + rq * 64 + lane) * DD);
#pragma unroll
        for (int j = 0; j < 4; j++) qf[rq][j] = qp[j];
    }
    float4 oacc[4][4];
#pragma unroll
    for (int rq = 0; rq < 4; rq++)
#pragma unroll
        for (int j = 0; j < 4; j++) oacc[rq][j] = make_float4(0.f, 0.f, 0.f, 0.f);
    float lsum[4] = {0.f, 0.f, 0.f, 0.f};

    float* sK = smem + w * 2048;
    float* sV = sK + 1024;

    // prologue: prefetch chunk 0 into registers
    float4 kpre[4], vpre[4];
    unsigned long long mwpre[4];
    {
        const float4* srcK = (const float4*)(Kb + (long long)(w * 256) * DD);
        const float4* srcV = (const float4*)(Vb + (long long)(w * 256) * DD);
#pragma unroll
        for (int i = 0; i < 4; i++) { kpre[i] = srcK[lane + 64 * i]; vpre[i] = srcV[lane + 64 * i]; }
#pragma unroll
        for (int rq = 0; rq < 4; rq++) mwpre[rq] = mrow[(long long)(w * 4) * NN + qbase + rq * 64 + lane];
    }

#pragma unroll
    for (int c = 0; c < 4; c++) {
        // stage prefetched chunk into wave-private LDS
#pragma unroll
        for (int i = 0; i < 4; i++) {
            ((float4*)sK)[lane + 64 * i] = kpre[i];
            ((float4*)sV)[lane + 64 * i] = vpre[i];
        }
        unsigned long long mw[4];
#pragma unroll
        for (int rq = 0; rq < 4; rq++) mw[rq] = mwpre[rq];
        // issue next chunk's loads; they complete during the ~4600-cycle inner loop below
        if (c < 3) {
            int kcn = w * 256 + (c + 1) * 64;
            const float4* srcK = (const float4*)(Kb + (long long)kcn * DD);
            const float4* srcV = (const float4*)(Vb + (long long)kcn * DD);
#pragma unroll
            for (int i = 0; i < 4; i++) { kpre[i] = srcK[lane + 64 * i]; vpre[i] = srcV[lane + 64 * i]; }
            int kblkn = w * 4 + c + 1;
#pragma unroll
            for (int rq = 0; rq < 4; rq++) mwpre[rq] = mrow[(long long)kblkn * NN + qbase + rq * 64 + lane];
        }
        // make this wave's LDS writes visible to its own lanes (wave-private -> no barrier)
        asm volatile("s_waitcnt lgkmcnt(0)" ::: "memory");
#pragma unroll 4
        for (int kk = 0; kk < 64; kk++) {
            const float4* kr = (const float4*)(sK + kk * 16);
            float4 k0 = kr[0], k1 = kr[1], k2 = kr[2], k3 = kr[3];
            float e[4];
#pragma unroll
            for (int rq = 0; rq < 4; rq++) {
                float4 a0 = qf[rq][0], a1 = qf[rq][1], a2 = qf[rq][2], a3 = qf[rq][3];
                float sA = a0.x * k0.x;
                sA = fmaf(a0.y, k0.y, sA); sA = fmaf(a0.z, k0.z, sA); sA = fmaf(a0.w, k0.w, sA);
                sA = fmaf(a1.x, k1.x, sA); sA = fmaf(a1.y, k1.y, sA); sA = fmaf(a1.z, k1.z, sA); sA = fmaf(a1.w, k1.w, sA);
                float sB = a2.x * k2.x;
                sB = fmaf(a2.y, k2.y, sB); sB = fmaf(a2.z, k2.z, sB); sB = fmaf(a2.w, k2.w, sB);
                sB = fmaf(a3.x, k3.x, sB); sB = fmaf(a3.y, k3.y, sB); sB = fmaf(a3.z, k3.z, sB); sB = fmaf(a3.w, k3.w, sB);
                float ee = __builtin_amdgcn_exp2f(sA + sB);     // softmax scale folded into Q
                e[rq] = ((mw[rq] >> kk) & 1ULL) ? 0.f : ee;
                lsum[rq] += e[rq];
            }
            const float4* vr = (const float4*)(sV + kk * 16);
            float4 v0 = vr[0], v1 = vr[1], v2 = vr[2], v3 = vr[3];
#pragma unroll
            for (int rq = 0; rq < 4; rq++) {
                float ew = e[rq];
                oacc[rq][0].x = fmaf(ew, v0.x, oacc[rq][0].x); oacc[rq][0].y = fmaf(ew, v0.y, oacc[rq][0].y);
                oacc[rq][0].z = fmaf(ew, v0.z, oacc[rq][0].z); oacc[rq][0].w = fmaf(ew, v0.w, oacc[rq][0].w);
                oacc[rq][1].x = fmaf(ew, v1.x, oacc[rq][1].x); oacc[rq][1].y = fmaf(ew, v1.y, oacc[rq][1].y);
                oacc[rq][1].z = fmaf(ew, v1.z, oacc[rq][1].z); oacc[rq][1].w = fmaf(ew, v1.w, oacc[rq][1].w);
                oacc[rq][2].x = fmaf(ew, v2.x, oacc[rq][2].x); oacc[rq][2].y = fmaf(ew, v2.y, oacc[rq][2].y);
                oacc[rq][2].z = fmaf(ew, v2.z, oacc[rq][2].z); oacc[rq][2].w = fmaf(ew, v2.w, oacc[rq][2].w);
                oacc[rq][3].x = fmaf(ew, v3.x, oacc[rq][3].x); oacc[rq][3].y = fmaf(ew, v3.y, oacc[rq][3].y);
                oacc[rq][3].z = fmaf(ew, v3.z, oacc[rq][3].z); oacc[rq][3].w = fmaf(ew, v3.w, oacc[rq][3].w);
            }
        }
    }
    __syncthreads();                                   // all staging reads done before overlay
#pragma unroll
    for (int rq = 0; rq < 4; rq++) {
        float* rp = smem + (((w * 4 + rq) * 64 + lane)) * 17;   // stride 17: 2 lanes/bank, free
#pragma unroll
        for (int j = 0; j < 4; j++) {
            rp[4 * j + 0] = oacc[rq][j].x; rp[4 * j + 1] = oacc[rq][j].y;
            rp[4 * j + 2] = oacc[rq][j].z; rp[4 * j + 3] = oacc[rq][j].w;
        }
        rp[16] = lsum[rq];
    }
    __syncthreads();
    if (w < 4) {
        int rq = w;
        float acc[DD]; float lt = 0.f;
#pragma unroll
        for (int d = 0; d < DD; d++) acc[d] = 0.f;
#pragma unroll
        for (int p = 0; p < 8; p++) {
            const float* pp = smem + (((p * 4 + rq) * 64 + lane)) * 17;
#pragma unroll
            for (int d = 0; d < DD; d++) acc[d] += pp[d];
            lt += pp[16];
        }
        float inv = 1.0f / lt;
        int q = qbase + rq * 64 + lane;
        float* op = O + (long long)(b * NN + q) * EE + h * DD;
        float4 r0 = {acc[0]*inv, acc[1]*inv, acc[2]*inv, acc[3]*inv};
        float4 r1 = {acc[4]*inv, acc[5]*inv, acc[6]*inv, acc[7]*inv};
        float4 r2 = {acc[8]*inv, acc[9]*inv, acc[10]*inv, acc[11]*inv};
        float4 r3 = {acc[12]*inv, acc[13]*inv, acc[14]*inv, acc[15]*inv};
        ((float4*)op)[0] = r0; ((float4*)op)[1] = r1; ((float4*)op)[2] = r2; ((float4*)op)[3] = r3;
    }
}

// ---------------- out-projection + ReLU (standalone, used for layer 1) ----------------
__global__ __launch_bounds__(256) void k_out(const float* __restrict__ X, const float* __restrict__ WO,
                                             const float* __restrict__ bO, float* __restrict__ Y) {
    int lane = threadIdx.x & 63, quarter = threadIdx.x >> 6;
    long long row = (long long)blockIdx.x * 64 + lane;
    float xr[64];
    const float4* xp = (const float4*)(X + row * 64);
#pragma unroll
    for (int i = 0; i < 16; i++) {
        float4 t = xp[i];
        xr[4 * i] = t.x; xr[4 * i + 1] = t.y; xr[4 * i + 2] = t.z; xr[4 * i + 3] = t.w;
    }
    for (int jq = 0; jq < 4; jq++) {
        int j = quarter * 16 + jq * 4;
        float4 acc = *(const float4*)(bO + j);
#pragma unroll
        for (int f = 0; f < 64; f++) {
            float4 w4 = *(const float4*)(WO + f * 64 + j);
            acc.x = fmaf(xr[f], w4.x, acc.x);
            acc.y = fmaf(xr[f], w4.y, acc.y);
            acc.z = fmaf(xr[f], w4.z, acc.z);
            acc.w = fmaf(xr[f], w4.w, acc.w);
        }
        acc.x = fmaxf(acc.x, 0.f); acc.y = fmaxf(acc.y, 0.f);
        acc.z = fmaxf(acc.z, 0.f); acc.w = fmaxf(acc.w, 0.f);
        *(float4*)(Y + row * 64 + j) = acc;
    }
}

// ---------------- fused: out-proj(L0)+ReLU -> QKV proj (L1), x1 never touches HBM ----------------
__global__ __launch_bounds__(256) void k_outqkv(const float* __restrict__ O, const float* __restrict__ WO,
                                                const float* __restrict__ bO,
                                                const float* __restrict__ CW, const float* __restrict__ bQ,
                                                float* __restrict__ Q, float* __restrict__ K, float* __restrict__ V) {
    __shared__ float xs[64 * 68];
    int lane = threadIdx.x & 63, quarter = threadIdx.x >> 6;
    long long row = (long long)blockIdx.x * 64 + lane;
    int b = (int)(row >> 11), n = (int)(row & (NN - 1));
    {
        float xr[64];
        const float4* xp = (const float4*)(O + row * 64);
#pragma unroll
        for (int i = 0; i < 16; i++) {
            float4 t = xp[i];
            xr[4 * i] = t.x; xr[4 * i + 1] = t.y; xr[4 * i + 2] = t.z; xr[4 * i + 3] = t.w;
        }
        for (int jq = 0; jq < 4; jq++) {
            int j = quarter * 16 + jq * 4;
            float4 acc = *(const float4*)(bO + j);
#pragma unroll
            for (int f = 0; f < 64; f++) {
                float4 w4 = *(const float4*)(WO + f * 64 + j);
                acc.x = fmaf(xr[f], w4.x, acc.x);
                acc.y = fmaf(xr[f], w4.y, acc.y);
                acc.z = fmaf(xr[f], w4.z, acc.z);
                acc.w = fmaf(xr[f], w4.w, acc.w);
            }
            acc.x = fmaxf(acc.x, 0.f); acc.y = fmaxf(acc.y, 0.f);
            acc.z = fmaxf(acc.z, 0.f); acc.w = fmaxf(acc.w, 0.f);
            *(float4*)(xs + lane * 68 + j) = acc;
        }
    }
    __syncthreads();
    {
        float xr[64];
        const float4* xp = (const float4*)(xs + lane * 68);
#pragma unroll
        for (int i = 0; i < 16; i++) {
            float4 t = xp[i];
            xr[4 * i] = t.x; xr[4 * i + 1] = t.y; xr[4 * i + 2] = t.z; xr[4 * i + 3] = t.w;
        }
        for (int jq = 0; jq < 12; jq++) {
            int j = quarter * 48 + jq * 4;
            float4 acc = *(const float4*)(bQ + j);
#pragma unroll
            for (int f = 0; f < 64; f++) {
                float4 w4 = *(const float4*)(CW + f * 192 + j);
                acc.x = fmaf(xr[f], w4.x, acc.x);
                acc.y = fmaf(xr[f], w4.y, acc.y);
                acc.z = fmaf(xr[f], w4.z, acc.z);
                acc.w = fmaf(xr[f], w4.w, acc.w);
            }
            int which = j >> 6, c = j & 63, h = c >> 4, d = c & 15;
            float* dst = (which == 0) ? Q : ((which == 1) ? K : V);
            *(float4*)(dst + (((long long)(b * HH + h) * NN + n) * DD + d)) = acc;
        }
    }
}

// ---------------- fused 3-layer MLP head v2: 2-pass stage2 (no 128-reg array), padded LDS ----------------
__global__ __launch_bounds__(128) void k_head(const float* __restrict__ X,
                                              const float* __restrict__ w1, const float* __restrict__ b1,
                                              const float* __restrict__ w2, const float* __restrict__ b2,
                                              const float* __restrict__ w3, const float* __restrict__ b3,
                                              float* __restrict__ out) {
    __shared__ float Xs[16 * 64];
    __shared__ float H1[16 * 132];                     // stride 132: 16B-aligned rows, 2-way banks (free)
    __shared__ float H2[16 * 132];
    int tid = threadIdx.x;
    long long row0 = (long long)blockIdx.x * 16;
    {
        const float4* src = (const float4*)(X + row0 * 64);
        float4* dst = (float4*)Xs;
        dst[tid] = src[tid];
        dst[tid + 128] = src[tid + 128];
    }
    __syncthreads();
    // stage 1: h1 = relu(X@w1 + b1), col = tid
    {
        float wr[64];
#pragma unroll
        for (int f = 0; f < 64; f++) wr[f] = w1[f * 128 + tid];
        float bb = b1[tid];
        for (int r = 0; r < 16; r++) {
            const float4* x4 = (const float4*)(Xs + r * 64);
            float a0 = bb, a1 = 0.f, a2 = 0.f, a3 = 0.f;
#pragma unroll
            for (int fq = 0; fq < 16; fq++) {
                float4 xv = x4[fq];
                a0 = fmaf(xv.x, wr[4 * fq], a0);
                a1 = fmaf(xv.y, wr[4 * fq + 1], a1);
                a2 = fmaf(xv.z, wr[4 * fq + 2], a2);
                a3 = fmaf(xv.w, wr[4 * fq + 3], a3);
            }
            H1[r * 132 + tid] = fmaxf((a0 + a1) + (a2 + a3), 0.f);
        }
    }
    __syncthreads();
    // stage 2: h2 = relu(h1@w2 + b2) — two passes over f so the w2-column cache is 64 regs
    {
        float acc2[16];
        float bb2 = b2[tid];
#pragma unroll
        for (int r = 0; r < 16; r++) acc2[r] = bb2;
#pragma unroll
        for (int p = 0; p < 2; p++) {
            float wr2[64];
#pragma unroll
            for (int i = 0; i < 64; i++) wr2[i] = w2[(p * 64 + i) * 128 + tid];
            for (int r = 0; r < 16; r++) {
                const float4* h4 = (const float4*)(H1 + r * 132 + p * 64);
                float a0 = 0.f, a1 = 0.f, a2 = 0.f, a3 = 0.f;
#pragma unroll
                for (int fq = 0; fq < 16; fq++) {
                    float4 xv = h4[fq];
                    a0 = fmaf(xv.x, wr2[4 * fq], a0);
                    a1 = fmaf(xv.y, wr2[4 * fq + 1], a1);
                    a2 = fmaf(xv.z, wr2[4 * fq + 2], a2);
                    a3 = fmaf(xv.w, wr2[4 * fq + 3], a3);
                }
                acc2[r] += (a0 + a1) + (a2 + a3);
            }
        }
#pragma unroll
        for (int r = 0; r < 16; r++) H2[r * 132 + tid] = fmaxf(acc2[r], 0.f);
    }
    __syncthreads();
    // stage 3: out = h2@w3 + b3 (A=4); H2 stride 132 -> banks vary with r (2-way, free)
    if (tid < 64) {
        int r = tid >> 2, a = tid & 3;
        float acc = b3[a];
        for (int f = 0; f < 128; f++) acc = fmaf(H2[r * 132 + f], w3[f * 4 + a], acc);
        out[(row0 + r) * 4 + a] = acc;
    }
}

extern "C" void kernel_launch(void* const* d_in, const int* in_sizes, int n_in,
                              void* d_out, int out_size, void* d_ws, size_t ws_size,
                              hipStream_t stream) {
    const float* nf = (const float*)d_in[0];
    const float* adj = (const float*)d_in[1];
    const float* l0[9]; for (int i = 0; i < 9; i++) l0[i] = (const float*)d_in[2 + i];
    const float* l1[9]; for (int i = 0; i < 9; i++) l1[i] = (const float*)d_in[11 + i];
    const float* hw1 = (const float*)d_in[20]; const float* hb1 = (const float*)d_in[21];
    const float* hw2 = (const float*)d_in[22]; const float* hb2 = (const float*)d_in[23];
    const float* hw3 = (const float*)d_in[24]; const float* hb3 = (const float*)d_in[25];
    float* out = (float*)d_out;

    char* ws = (char*)d_ws;
    size_t off = 0;
    auto alloc = [&](size_t bytes) -> void* {
        void* p = ws + off;
        off = (off + bytes + 255) & ~(size_t)255;
        return p;
    };
    unsigned long long* mbT = (unsigned long long*)alloc((size_t)BB * NN * NN / 8);
    float* Q = (float*)alloc((size_t)BB * HH * NN * DD * 4);
    float* K = (float*)alloc((size_t)BB * HH * NN * DD * 4);
    float* V = (float*)alloc((size_t)BB * HH * NN * DD * 4);
    float* O = (float*)alloc((size_t)BB * NN * EE * 4);
    float* x2 = (float*)alloc((size_t)BB * NN * EE * 4);
    float* CW0 = (float*)alloc(16 * 192 * 4);
    float* CW1 = (float*)alloc(64 * 192 * 4);
    float* WO0 = (float*)alloc(64 * 64 * 4);
    float* WO1 = (float*)alloc(64 * 64 * 4);
    float* bO0 = (float*)alloc(64 * 4);
    float* bO1 = (float*)alloc(64 * 4);
    float* bQ0 = (float*)alloc(192 * 4);
    float* bQ1 = (float*)alloc(192 * 4);

    k_mask<<<4096, 256, 0, stream>>>(adj, mbT);
    k_wcomb<<<dim3(65, 2), 256, 0, stream>>>(
        l0[0], l0[1], l0[2], l0[3], l0[4], l0[5], l0[6], l0[7], l0[8],
        l1[0], l1[1], l1[2], l1[3], l1[4], l1[5], l1[6], l1[7], l1[8],
        CW0, WO0, bO0, bQ0, CW1, WO1, bO1, bQ1);

    // layer 0 (feature scale folded into CW0)
    k_qkv<16><<<BB * NN / 64, 256, 0, stream>>>(nf, CW0, bQ0, Q, K, V);
    k_attn<<<dim3(NN / 256, HH, BB), 512, 0, stream>>>(Q, K, V, mbT, O);
    // fused: out-proj L0 + QKV proj L1
    k_outqkv<<<BB * NN / 64, 256, 0, stream>>>(O, WO0, bO0, CW1, bQ1, Q, K, V);
    k_attn<<<dim3(NN / 256, HH, BB), 512, 0, stream>>>(Q, K, V, mbT, O);
    k_out<<<BB * NN / 64, 256, 0, stream>>>(O, WO1, bO1, x2);
    // head
    k_head<<<BB * NN / 16, 128, 0, stream>>>(x2, hw1, hb1, hw2, hb2, hw3, hb3, out);
}